// Round 3
// baseline (75.139 us; speedup 1.0000x reference)
//
#include <hip/hip_runtime.h>

// YOLOv1 loss: pre/lab [32768, 30, 7, 7] fp32 -> scalar (sum / B).
// Round 3: round-2 was latency-serialized (stage -> barrier -> compute, no
// overlap; 19% HBM BW, 12% VALU). Now:
//  - cls term (channels 10..29, 2/3 of bytes) is elementwise: computed
//    directly from float4 registers during staging, never touches LDS.
//  - only channels 0..9 (first 490 floats/batch) go to LDS for the
//    cell-coupled obj/noobj terms.
//  - double-buffered: issue loads(t+1) -> compute cells(t) -> consume(t+1)
//    (cls-acc + ds_write) -> one barrier. Load latency hides under compute.

#define BATCH   32768
#define S2      49            // 7*7 cells per batch
#define CPB     1470          // floats per batch per tensor (30*49)
#define NB      2             // batches per group
#define GF      (NB * CPB)    // 2940 floats per group per tensor
#define GV      (GF / 4)      // 735 float4 per group per tensor
#define NGROUPS (BATCH / NB)  // 16384
#define LDSB    492           // padded floats per batch in LDS (16B-aligned)
#define HALF    (NB * LDSB)   // 984: one tensor's LDS region (floats)
#define BUFSZ   (2 * HALF)    // 1968 floats per buffer (7872 B)
#define NBLK    2048

__device__ __forceinline__ float iou4(float px1, float py1, float px2, float py2,
                                      float lx1, float ly1, float lx2, float ly2) {
    float ix1 = fmaxf(px1, lx1), iy1 = fmaxf(py1, ly1);
    float ix2 = fminf(px2, lx2), iy2 = fminf(py2, ly2);
    float iw = fmaxf(ix2 - ix1 + 1.0f, 0.0f);
    float ih = fmaxf(iy2 - iy1 + 1.0f, 0.0f);
    float inter = iw * ih;
    float a1 = (px2 - px1 + 1.0f) * (py2 - py1 + 1.0f);
    float a2 = (lx2 - lx1 + 1.0f) * (ly2 - ly1 + 1.0f);
    return inter / (a1 + a2 - inter);
}

// obj/noobj terms for one cell; P,L point at (batch-slot, s) inside LDS,
// channel stride 49 (conflict-free: consecutive threads -> consecutive banks).
__device__ __forceinline__ float cell_loss(const float* P, const float* L) {
    float p0 = P[0],   p1 = P[49],  p2 = P[98],  p3 = P[147], p4 = P[196];
    float p5 = P[245], p6 = P[294], p7 = P[343], p8 = P[392], p9 = P[441];
    float l0 = L[0],   l1 = L[49],  l2 = L[98],  l3 = L[147], l4 = L[196];
    float l5 = L[245], l6 = L[294], l7 = L[343], l8 = L[392];

    float iou1 = iou4(p0, p1, p2, p3, l0, l1, l2, l3);
    float iou2 = iou4(p5, p6, p7, p8, l5, l6, l7, l8);
    bool resp1 = iou1 >= iou2;

    float d0 = l0 - p0, d1 = l1 - p1, d5 = l5 - p5, d6 = l6 - p6;
    float addr1 = 5.0f * (d0 * d0 + d1 * d1);
    float addr2 = 5.0f * (d5 * d5 + d6 * d6);

    float e2 = sqrtf(p2) - sqrtf(l2), e3 = sqrtf(p3) - sqrtf(l3);
    float e7 = sqrtf(p7) - sqrtf(l7), e8 = sqrtf(p8) - sqrtf(l8);
    float size1 = 5.0f * (e2 * e2 + e3 * e3);
    float size2 = 5.0f * (e7 * e7 + e8 * e8);

    float du = p9 - (resp1 ? iou1 : iou2);
    float conf = 0.5f * du * du;

    float obj_terms = (resp1 ? (addr1 + size1) : (addr2 + size2)) + conf;
    float pn = p4 + p9;
    float noobj = 0.5f * pn * pn;
    return (l4 == 1.0f) ? obj_terms : noobj;
}

// Route one float4 pair: coupled channels (lo<490) -> LDS, cls -> acc.
__device__ __forceinline__ void consume_one(float4 pv, float4 lv, int i,
                                            float* buf, float& acc) {
    int base = 4 * i;                 // group-local float index (0..2936), even
    int bl = base >= CPB;
    int lo = base - bl * CPB;
    if (lo <= 486) {                  // all 4 elements coupled, same batch
        *(float4*)(buf + bl * LDSB + lo) = pv;
        *(float4*)(buf + HALF + bl * LDSB + lo) = lv;
    } else if (lo >= 490 && lo <= 1466) {   // all 4 elements cls
        float d0 = pv.x - lv.x, d1 = pv.y - lv.y;
        float d2 = pv.z - lv.z, d3 = pv.w - lv.w;
        acc += d0 * d0 + d1 * d1 + d2 * d2 + d3 * d3;
    } else {                          // mixed (lo==488 or lo==1468): rare
        float pe[4] = {pv.x, pv.y, pv.z, pv.w};
        float le[4] = {lv.x, lv.y, lv.z, lv.w};
        #pragma unroll
        for (int e = 0; e < 4; ++e) {
            int f = base + e;
            int b2 = f >= CPB;
            int l2 = f - b2 * CPB;
            if (l2 < 490) {
                buf[b2 * LDSB + l2] = pe[e];
                buf[HALF + b2 * LDSB + l2] = le[e];
            } else {
                float d = pe[e] - le[e];
                acc += d * d;
            }
        }
    }
}

__global__ __launch_bounds__(256) void yolo_loss_main(const float4* __restrict__ pre4,
                                                      const float4* __restrict__ lab4,
                                                      float* __restrict__ partials) {
    __shared__ __align__(16) float sbuf[2 * BUFSZ];
    __shared__ float red[4];
    const int tid = threadIdx.x;
    float acc = 0.0f;

    float* cb   = sbuf;           // compute buffer
    float* nbuf = sbuf + BUFSZ;   // staging target

    int g = blockIdx.x;
    {   // prologue: stage group g into cb
        const float4* __restrict__ ps = pre4 + (size_t)g * GV;
        const float4* __restrict__ ls = lab4 + (size_t)g * GV;
        float4 pv[3], lv[3];
        #pragma unroll
        for (int k = 0; k < 3; ++k) {
            int i = tid + 256 * k;
            if (i < GV) { pv[k] = ps[i]; lv[k] = ls[i]; }
        }
        #pragma unroll
        for (int k = 0; k < 3; ++k) {
            int i = tid + 256 * k;
            if (i < GV) consume_one(pv[k], lv[k], i, cb, acc);
        }
    }
    __syncthreads();

    for (;;) {
        int gn = g + gridDim.x;
        bool hn = gn < NGROUPS;
        float4 pv[3], lv[3];
        if (hn) {   // issue loads for group t+1 FIRST (latency hides under cells)
            const float4* __restrict__ ps = pre4 + (size_t)gn * GV;
            const float4* __restrict__ ls = lab4 + (size_t)gn * GV;
            #pragma unroll
            for (int k = 0; k < 3; ++k) {
                int i = tid + 256 * k;
                if (i < GV) { pv[k] = ps[i]; lv[k] = ls[i]; }
            }
        }
        // compute cells of group t from cb
        if (tid < NB * S2) {
            int bl = tid / S2, s = tid - bl * S2;
            acc += cell_loss(cb + bl * LDSB + s, cb + HALF + bl * LDSB + s);
        }
        // consume loads: cls-acc + ds_write into nbuf
        if (hn) {
            #pragma unroll
            for (int k = 0; k < 3; ++k) {
                int i = tid + 256 * k;
                if (i < GV) consume_one(pv[k], lv[k], i, nbuf, acc);
            }
        }
        __syncthreads();
        if (!hn) break;
        g = gn;
        float* t = cb; cb = nbuf; nbuf = t;
    }

    // wave butterfly reduce, then cross-wave via LDS (deterministic)
    #pragma unroll
    for (int off = 32; off > 0; off >>= 1) acc += __shfl_down(acc, off);
    int lane = tid & 63, wid = tid >> 6;
    if (lane == 0) red[wid] = acc;
    __syncthreads();
    if (tid == 0) partials[blockIdx.x] = red[0] + red[1] + red[2] + red[3];
}

__global__ __launch_bounds__(256) void yolo_loss_final(const float* __restrict__ partials,
                                                       int n, float* __restrict__ out) {
    double v = 0.0;
    for (int i = (int)threadIdx.x; i < n; i += 256) v += (double)partials[i];
    __shared__ double sm[256];
    sm[threadIdx.x] = v;
    __syncthreads();
    for (int s = 128; s > 0; s >>= 1) {
        if ((int)threadIdx.x < s) sm[threadIdx.x] += sm[threadIdx.x + s];
        __syncthreads();
    }
    if (threadIdx.x == 0) out[0] = (float)(sm[0] * (1.0 / (double)BATCH));
}

extern "C" void kernel_launch(void* const* d_in, const int* in_sizes, int n_in,
                              void* d_out, int out_size, void* d_ws, size_t ws_size,
                              hipStream_t stream) {
    const float4* pre4 = (const float4*)d_in[0];
    const float4* lab4 = (const float4*)d_in[1];
    float* out = (float*)d_out;
    float* partials = (float*)d_ws;

    int nblk = NBLK;
    if (ws_size < (size_t)nblk * sizeof(float)) {
        nblk = (int)(ws_size / sizeof(float));
        if (nblk < 1) nblk = 1;
    }

    yolo_loss_main<<<nblk, 256, 0, stream>>>(pre4, lab4, partials);
    yolo_loss_final<<<1, 256, 0, stream>>>(partials, nblk, out);
}